// Round 7
// baseline (269.656 us; speedup 1.0000x reference)
//
#include <hip/hip_runtime.h>
#include <hip/hip_bf16.h>

constexpr int BB = 32;    // batch
constexpr int TT = 512;   // decode steps
constexpr int NN = 512;   // nodes
constexpr int DD = 256;   // model dim
constexpr int HH = 8;     // heads
constexpr int DH = 32;    // head dim
#define NEG_INF (-1e9f)

typedef __attribute__((ext_vector_type(8))) short bf16x8;
typedef __attribute__((ext_vector_type(4))) short bf16x4;
typedef __attribute__((ext_vector_type(4))) float f32x4;

__device__ inline ushort f2bf(float x) {
    union { float f; unsigned u; } c; c.f = x;
    unsigned u = c.u + 0x7fffu + ((c.u >> 16) & 1u);  // RNE
    return (ushort)(u >> 16);
}
__device__ inline uint pk2(float a, float b) {
    return (uint)f2bf(a) | ((uint)f2bf(b) << 16);
}
__device__ inline float ulo(uint u) {
    union { uint u; float f; } c; c.u = u << 16; return c.f;
}
__device__ inline float uhi(uint u) {
    union { uint u; float f; } c; c.u = u & 0xffff0000u; return c.f;
}
__device__ inline float fast_tanh10(float x) {
    x = fminf(fmaxf(x, -20.f), 20.f);
    float e2 = __expf(2.f * x);
    return 10.f * (1.f - 2.f / (e2 + 1.f));
}

// ---------------------------------------------------------------------------
// P0': fused emb fp32->bf16 convert + per-(b,part) partial sums. grid (BB,8).
__global__ __launch_bounds__(256) void cvt_ctx_k(const float* __restrict__ emb,
                                                 ushort* __restrict__ embB,
                                                 float* __restrict__ partial) {
    int b = blockIdx.x, part = blockIdx.y, d = threadIdx.x;
    const float* eb = emb + ((size_t)b * NN + part * 64) * DD + d;
    ushort* ob = embB + ((size_t)b * NN + part * 64) * DD + d;
    float s = 0.f;
    #pragma unroll 4
    for (int i = 0; i < 64; i++) {
        float v = eb[(size_t)i * DD];
        s += v;
        ob[(size_t)i * DD] = f2bf(v);
    }
    partial[((size_t)b * 8 + part) * DD + d] = s;
}

// P1': all three weight transposes in one launch. grid (40, 8), block (32,8).
__global__ void twt_all_k(const float* __restrict__ Wn,
                          const float* __restrict__ Ws,
                          const float* __restrict__ Wo,
                          ushort* __restrict__ WnT, ushort* __restrict__ WsT,
                          ushort* __restrict__ WoT) {
    __shared__ float t[32][33];
    int gx = blockIdx.x;
    const float* W;
    ushort* WT;
    int NC, xb;
    if (gx < 24)      { W = Wn; WT = WnT; NC = 768; xb = gx; }
    else if (gx < 32) { W = Ws; WT = WsT; NC = 256; xb = gx - 24; }
    else              { W = Wo; WT = WoT; NC = 256; xb = gx - 32; }
    int tx = threadIdx.x, ty = threadIdx.y;
    int x = xb * 32 + tx;
    int y0 = blockIdx.y * 32;
    #pragma unroll
    for (int j = 0; j < 4; j++)
        t[ty + j * 8][tx] = W[(size_t)(y0 + ty + j * 8) * NC + x];
    __syncthreads();
    #pragma unroll
    for (int j = 0; j < 4; j++)
        WT[(size_t)(xb * 32 + ty + j * 8) * 256 + y0 + tx] =
            f2bf(t[tx][ty + j * 8]);
}

// P2: mask -> bit-packed mbt [B*T][16]; word w bit c = mask[row][c*16+w]
__global__ __launch_bounds__(256) void packmask_k(const int* __restrict__ mask,
                                                  uint* __restrict__ mbt) {
    int idx = blockIdx.x * 256 + threadIdx.x;
    int row = idx >> 4, w = idx & 15;
    const int* mr = mask + (size_t)row * NN + w;
    uint u = 0;
    #pragma unroll
    for (int c = 0; c < 32; c++) u |= (uint)(mr[c * 16] != 0) << c;
    mbt[idx] = u;
}

// K0b: ctx = mean @ W_fixed; grid BB
__global__ __launch_bounds__(256) void ctx_mm_k(const float* __restrict__ partial,
                                                const float* __restrict__ Wf,
                                                float* __restrict__ ctx) {
    int b = blockIdx.x, d = threadIdx.x;
    __shared__ float ms[256];
    float s = 0.f;
    #pragma unroll
    for (int p = 0; p < 8; p++) s += partial[((size_t)b * 8 + p) * DD + d];
    ms[d] = s * (1.0f / NN);
    __syncthreads();
    float acc = 0.f;
    #pragma unroll 8
    for (int k = 0; k < 256; k++) acc += ms[k] * Wf[(size_t)k * DD + d];
    ctx[(size_t)b * DD + d] = acc;
}

// ---------------------------------------------------------------------------
// MFMA GEMM: C[M,256*?] = A[M,256](bf16) @ W via WT[NC][256] bf16.
// 1-D grid j: x = j&255 (row panel), y = j>>8 (col group).
template <int GATHER, int BIAS, int SPLIT>
__global__ __launch_bounds__(256) void gemm_mfma_k(
    const ushort* __restrict__ A, const ushort* __restrict__ WT,
    ushort* __restrict__ O0, ushort* __restrict__ O1, ushort* __restrict__ O2,
    const float* __restrict__ bias, const int* __restrict__ gidx, int CPB) {
    int j = blockIdx.x;
    int bx = j & 255, by = j >> 8;
    int tid = threadIdx.x;
    int w = tid >> 6, l = tid & 63;
    int lo = l & 15, hi = l >> 4;
    int row0 = bx * 64 + w * 16;
    int arow = row0 + lo;
    const ushort* ap;
    if (GATHER) {
        int b = arow >> 9;
        int node = gidx[arow];
        ap = A + ((size_t)(b * NN + node)) * DD;
    } else {
        ap = A + (size_t)arow * DD;
    }
    bf16x8 af[8];
    #pragma unroll
    for (int ks = 0; ks < 8; ks++)
        af[ks] = *(const bf16x8*)(ap + ks * 32 + hi * 8);

    const f32x4 zero = {0.f, 0.f, 0.f, 0.f};
    for (int c = 0; c < CPB; c++) {
        int cg = by * CPB + c;
        int col = cg * 16 + lo;
        const ushort* bp = WT + (size_t)col * 256 + hi * 8;
        f32x4 acc = zero;
        #pragma unroll
        for (int ks = 0; ks < 8; ks++)
            acc = __builtin_amdgcn_mfma_f32_16x16x32_bf16(
                af[ks], *(const bf16x8*)(bp + ks * 32), acc, 0, 0, 0);
        float v[4];
        #pragma unroll
        for (int r = 0; r < 4; r++) {
            v[r] = acc[r];
            if (BIAS) v[r] += bias[(size_t)(row0 >> 9) * DD + col];
        }
        if (SPLIT == 0) {
            #pragma unroll
            for (int r = 0; r < 4; r++)
                O0[(size_t)(row0 + 4 * hi + r) * DD + col] = f2bf(v[r]);
        } else {
            if (col < 256) {
                #pragma unroll
                for (int r = 0; r < 4; r++)
                    O0[(size_t)(row0 + 4 * hi + r) * 256 + col] = f2bf(v[r]);
            } else if (col < 512) {
                int cc = col - 256;
                int bh = (row0 >> 9) * HH + (cc >> 5);
                int dh = cc & 31;
                int n0 = (row0 + 4 * hi) & (NN - 1);
                ushort4 uv = {f2bf(v[0]), f2bf(v[1]), f2bf(v[2]), f2bf(v[3])};
                *(ushort4*)(O1 + ((size_t)bh * DH + dh) * NN + n0) = uv;
            } else {
                #pragma unroll
                for (int r = 0; r < 4; r++)
                    O2[(size_t)(row0 + 4 * hi + r) * 256 + (col - 512)] = f2bf(v[r]);
            }
        }
    }
}

// ---------------------------------------------------------------------------
// K3: swapped-operand MFMA attention, zero P movement.
// sT[c] = mfma(K_frag, Q_frag): lane(lo,hi) holds S^T[n=c*16+4hi+r][q=lo].
// e-values packed in-lane form the PV B-fragment directly via the k-slot map
// k=8hi+i -> n = 32p + 16*(i>=4) + 4hi + (i&3); A-operand = V^T rows (dh=lo).
// O^T accum in regs; per-wave 5KB LDS transpose for the coalesced heads write.
// No max subtraction (|s*sc| <~ 12, f32 exp safe; verified r5/r6).
// grid j: bh = j&255, qc = j>>8 (XCD locality for K/V).
__global__ __launch_bounds__(256, 4) void attn6_k(
    const ushort* __restrict__ gq, const ushort* __restrict__ gk,
    const ushort* __restrict__ vT, const uint* __restrict__ mbt,
    ushort* __restrict__ headsB) {
    int j = blockIdx.x;
    int bh = j & 255, qc = j >> 8;
    int b = bh >> 3, h = bh & 7;
    int tid = threadIdx.x;
    int w = tid >> 6, l = tid & 63;
    int lo = l & 15, hi = l >> 4;
    int t0 = qc * 64 + w * 16;

    __shared__ ushort OT[4][16][40];  // [wave][q][dh] pad->16B-aligned rows

    const f32x4 zero = {0.f, 0.f, 0.f, 0.f};
    const float sc = 0.17677669529663687f;  // 1/sqrt(32)

    // Q as B-fragment: col = q = t0+lo, k = dh = 8hi+i
    bf16x8 qf = *(const bf16x8*)(gq + ((size_t)(b * TT + t0 + lo)) * DD + h * DH + hi * 8);
    // mask words for (q=lo, n=c*16+4hi+r): word 4hi+r of q's row, bit c
    uint4 mq = *(const uint4*)(mbt + ((size_t)(b * TT + t0 + lo)) * 16 + 4 * hi);

    const ushort* kb = gk + (size_t)b * NN * DD + h * DH + hi * 8;
    const ushort* v0 = vT + ((size_t)(b * HH + h) * DH + lo) * NN;  // dh = lo
    const ushort* v1 = v0 + (size_t)16 * NN;                        // dh = 16+lo

    float sum = 0.f;
    f32x4 o0 = zero, o1 = zero;

    #pragma unroll
    for (int p = 0; p < 16; p++) {  // pair of 16-key chunks = 32 keys
        union { bf16x8 v; uint u[4]; } pf;
        {
            const int c = 2 * p;
            bf16x8 kf = *(const bf16x8*)(kb + (size_t)(c * 16 + lo) * DD);
            f32x4 s = __builtin_amdgcn_mfma_f32_16x16x32_bf16(kf, qf, zero, 0, 0, 0);
            float e0 = ((mq.x >> c) & 1u) ? __expf(s[0] * sc) : 0.f;
            float e1 = ((mq.y >> c) & 1u) ? __expf(s[1] * sc) : 0.f;
            float e2 = ((mq.z >> c) & 1u) ? __expf(s[2] * sc) : 0.f;
            float e3 = ((mq.w >> c) & 1u) ? __expf(s[3] * sc) : 0.f;
            sum += (e0 + e1) + (e2 + e3);
            pf.u[0] = pk2(e0, e1);
            pf.u[1] = pk2(e2, e3);
        }
        {
            const int c = 2 * p + 1;
            bf16x8 kf = *(const bf16x8*)(kb + (size_t)(c * 16 + lo) * DD);
            f32x4 s = __builtin_amdgcn_mfma_f32_16x16x32_bf16(kf, qf, zero, 0, 0, 0);
            float e0 = ((mq.x >> c) & 1u) ? __expf(s[0] * sc) : 0.f;
            float e1 = ((mq.y >> c) & 1u) ? __expf(s[1] * sc) : 0.f;
            float e2 = ((mq.z >> c) & 1u) ? __expf(s[2] * sc) : 0.f;
            float e3 = ((mq.w >> c) & 1u) ? __expf(s[3] * sc) : 0.f;
            sum += (e0 + e1) + (e2 + e3);
            pf.u[2] = pk2(e0, e1);
            pf.u[3] = pk2(e2, e3);
        }
        // V^T A-fragments: element i at n = 32p + 16*(i>=4) + 4hi + (i&3)
        bf16x4 a00 = *(const bf16x4*)(v0 + 32 * p + 4 * hi);
        bf16x4 a01 = *(const bf16x4*)(v0 + 32 * p + 16 + 4 * hi);
        bf16x4 a10 = *(const bf16x4*)(v1 + 32 * p + 4 * hi);
        bf16x4 a11 = *(const bf16x4*)(v1 + 32 * p + 16 + 4 * hi);
        bf16x8 va0 = {a00[0], a00[1], a00[2], a00[3], a01[0], a01[1], a01[2], a01[3]};
        bf16x8 va1 = {a10[0], a10[1], a10[2], a10[3], a11[0], a11[1], a11[2], a11[3]};
        o0 = __builtin_amdgcn_mfma_f32_16x16x32_bf16(va0, pf.v, o0, 0, 0, 0);
        o1 = __builtin_amdgcn_mfma_f32_16x16x32_bf16(va1, pf.v, o1, 0, 0, 0);
    }

    // denom for q = lo: reduce across hi groups only
    sum += __shfl_xor(sum, 16);
    sum += __shfl_xor(sum, 32);
    float inv = 1.0f / fmaxf(sum, 1e-30f);

    // O^T[dh=4hi+r (+16)][q=lo] -> LDS transpose -> coalesced bf16x8 write
    #pragma unroll
    for (int r = 0; r < 4; r++) {
        OT[w][lo][4 * hi + r] = f2bf(o0[r] * inv);
        OT[w][lo][16 + 4 * hi + r] = f2bf(o1[r] * inv);
    }
    // wave-private slice: in-wave ds ordering suffices (no barrier needed)
    bf16x8 ov = *(const bf16x8*)(&OT[w][lo][hi * 8]);
    *(bf16x8*)(headsB + ((size_t)(b * TT + t0 + lo)) * DD + h * DH + hi * 8) = ov;
}

// ---------------------------------------------------------------------------
// K5: MFMA pointer logits + log_softmax with FIXED max = 10 (tanh bound).
// grid j: b = j&31, tc = j>>5.
__global__ __launch_bounds__(256) void logits4_k(
    const ushort* __restrict__ glimpse, const ushort* __restrict__ lk,
    const uint* __restrict__ mbt, float* __restrict__ out) {
    int j = blockIdx.x;  // B * T/16
    int b = j & 31;
    int t0 = (j >> 5) * 16;
    int tid = threadIdx.x;
    int w = tid >> 6, l = tid & 63;
    int lo = l & 15, hi = l >> 4;

    __shared__ float reds[4][16];

    bf16x8 af[8];
    const ushort* gb = glimpse + ((size_t)(b * TT + t0 + lo)) * DD + hi * 8;
    #pragma unroll
    for (int ks = 0; ks < 8; ks++) af[ks] = *(const bf16x8*)(gb + ks * 32);
    uint mw[4];
    #pragma unroll
    for (int r = 0; r < 4; r++)
        mw[r] = mbt[((size_t)(b * TT + t0 + 4 * hi + r)) * 16 + lo];

    const f32x4 zero = {0.f, 0.f, 0.f, 0.f};
    const ushort* lkb = lk + (size_t)b * NN * DD + hi * 8;
    float sum[4] = {0.f, 0.f, 0.f, 0.f};
    uint tu[16];
    #pragma unroll
    for (int cl = 0; cl < 8; cl++) {
        int c = w * 8 + cl;
        f32x4 acc = zero;
        const ushort* kr = lkb + (size_t)(c * 16 + lo) * DD;
        #pragma unroll
        for (int ks = 0; ks < 8; ks++)
            acc = __builtin_amdgcn_mfma_f32_16x16x32_bf16(
                af[ks], *(const bf16x8*)(kr + ks * 32), acc, 0, 0, 0);
        float t[4];
        #pragma unroll
        for (int r = 0; r < 4; r++) {
            t[r] = fast_tanh10(acc[r] * 0.0625f);
            sum[r] += ((mw[r] >> c) & 1u) ? __expf(t[r] - 10.f) : 0.f;
        }
        tu[2 * cl] = pk2(t[0], t[1]);
        tu[2 * cl + 1] = pk2(t[2], t[3]);
    }
    #pragma unroll
    for (int r = 0; r < 4; r++)
        #pragma unroll
        for (int o = 1; o < 16; o <<= 1) sum[r] += __shfl_xor(sum[r], o);
    if (lo == 0) {
        #pragma unroll
        for (int r = 0; r < 4; r++) reds[w][4 * hi + r] = sum[r];
    }
    __syncthreads();
    float lse[4];
    #pragma unroll
    for (int r = 0; r < 4; r++) {
        int row = 4 * hi + r;
        float s = reds[0][row] + reds[1][row] + reds[2][row] + reds[3][row];
        lse[r] = 10.f + __logf(fmaxf(s, 1e-37f));
    }

    #pragma unroll
    for (int cl = 0; cl < 8; cl++) {
        int c = w * 8 + cl;
        float v[4] = {ulo(tu[2 * cl]), uhi(tu[2 * cl]),
                      ulo(tu[2 * cl + 1]), uhi(tu[2 * cl + 1])};
        #pragma unroll
        for (int r = 0; r < 4; r++) {
            float ov = ((mw[r] >> c) & 1u) ? v[r] - lse[r] : NEG_INF - lse[r];
            out[((size_t)(b * TT + t0 + 4 * hi + r)) * NN + c * 16 + lo] = ov;
        }
    }
}

// ---------------------------------------------------------------------------
extern "C" void kernel_launch(void* const* d_in, const int* in_sizes, int n_in,
                              void* d_out, int out_size, void* d_ws,
                              size_t ws_size, hipStream_t stream) {
    const float* emb = (const float*)d_in[0];
    const int* cur   = (const int*)d_in[1];
    const int* mask  = (const int*)d_in[2];
    const float* Wn  = (const float*)d_in[3];
    const float* Wf  = (const float*)d_in[4];
    const float* Ws  = (const float*)d_in[5];
    const float* Wo  = (const float*)d_in[6];
    float* out = (float*)d_out;

    const size_t SLABE = (size_t)BB * NN * DD;
    ushort* embB     = (ushort*)d_ws;
    ushort* gk       = embB + SLABE;
    ushort* vT       = gk + SLABE;
    ushort* lkb      = vT + SLABE;
    ushort* gq       = lkb + SLABE;
    ushort* headsB   = gq + SLABE;
    ushort* glimpseB = headsB + SLABE;
    ushort* WnT      = glimpseB + SLABE;
    ushort* WsT      = WnT + 768 * 256;
    ushort* WoT      = WsT + 256 * 256;
    uint*   mbt      = (uint*)(WoT + 256 * 256);
    float*  ctx      = (float*)(mbt + (size_t)BB * TT * 16);
    float*  partial  = ctx + (size_t)BB * DD;

    // prep (fused)
    cvt_ctx_k<<<dim3(BB, 8), 256, 0, stream>>>(emb, embB, partial);
    twt_all_k<<<dim3(40, 8), dim3(32, 8), 0, stream>>>(Wn, Ws, Wo, WnT, WsT, WoT);
    packmask_k<<<BB * TT * 16 / 256, 256, 0, stream>>>(mask, mbt);
    ctx_mm_k<<<BB, 256, 0, stream>>>(partial, Wf, ctx);

    // K1: proj = emb @ W_node -> gk / vT / lk
    gemm_mfma_k<0, 0, 1><<<3072, 256, 0, stream>>>(
        embB, WnT, gk, vT, lkb, nullptr, nullptr, 4);
    // K2: glimpse_q = emb[cur] @ W_step + ctx -> gq
    gemm_mfma_k<1, 1, 0><<<1024, 256, 0, stream>>>(
        embB, WsT, gq, nullptr, nullptr, ctx, cur, 4);
    // K3: attention -> headsB (swapped-operand, zero P movement)
    attn6_k<<<BB * HH * 8, 256, 0, stream>>>(gq, gk, vT, mbt, headsB);
    // K4: glimpse = heads @ W_out
    gemm_mfma_k<0, 0, 0><<<1024, 256, 0, stream>>>(
        headsB, WoT, glimpseB, nullptr, nullptr, nullptr, nullptr, 4);
    // K5: pointer logits + log_softmax
    logits4_k<<<BB * TT / 16, 256, 0, stream>>>(glimpseB, lkb, mbt, out);
}

// Round 8
// 215.081 us; speedup vs baseline: 1.2537x; 1.2537x over previous
//
#include <hip/hip_runtime.h>
#include <hip/hip_bf16.h>

constexpr int BB = 32;    // batch
constexpr int TT = 512;   // decode steps
constexpr int NN = 512;   // nodes
constexpr int DD = 256;   // model dim
constexpr int HH = 8;     // heads
constexpr int DH = 32;    // head dim
#define NEG_INF (-1e9f)

typedef __attribute__((ext_vector_type(8))) short bf16x8;
typedef __attribute__((ext_vector_type(4))) float f32x4;

__device__ inline ushort f2bf(float x) {
    union { float f; unsigned u; } c; c.f = x;
    unsigned u = c.u + 0x7fffu + ((c.u >> 16) & 1u);  // RNE
    return (ushort)(u >> 16);
}
__device__ inline uint pk2(float a, float b) {
    return (uint)f2bf(a) | ((uint)f2bf(b) << 16);
}
__device__ inline float ulo(uint u) {
    union { uint u; float f; } c; c.u = u << 16; return c.f;
}
__device__ inline float uhi(uint u) {
    union { uint u; float f; } c; c.u = u & 0xffff0000u; return c.f;
}
__device__ inline float fast_tanh10(float x) {
    x = fminf(fmaxf(x, -20.f), 20.f);
    float e2 = __expf(2.f * x);
    return 10.f * (1.f - 2.f / (e2 + 1.f));
}

// ---------------------------------------------------------------------------
// P0': fused emb fp32->bf16 convert + per-(b,part) partial sums. grid (BB,8).
__global__ __launch_bounds__(256) void cvt_ctx_k(const float* __restrict__ emb,
                                                 ushort* __restrict__ embB,
                                                 float* __restrict__ partial) {
    int b = blockIdx.x, part = blockIdx.y, d = threadIdx.x;
    const float* eb = emb + ((size_t)b * NN + part * 64) * DD + d;
    ushort* ob = embB + ((size_t)b * NN + part * 64) * DD + d;
    float s = 0.f;
    #pragma unroll 4
    for (int i = 0; i < 64; i++) {
        float v = eb[(size_t)i * DD];
        s += v;
        ob[(size_t)i * DD] = f2bf(v);
    }
    partial[((size_t)b * 8 + part) * DD + d] = s;
}

// P1': all three weight transposes in one launch. grid (40, 8), block (32,8).
__global__ void twt_all_k(const float* __restrict__ Wn,
                          const float* __restrict__ Ws,
                          const float* __restrict__ Wo,
                          ushort* __restrict__ WnT, ushort* __restrict__ WsT,
                          ushort* __restrict__ WoT) {
    __shared__ float t[32][33];
    int gx = blockIdx.x;
    const float* W;
    ushort* WT;
    int NC, xb;
    if (gx < 24)      { W = Wn; WT = WnT; NC = 768; xb = gx; }
    else if (gx < 32) { W = Ws; WT = WsT; NC = 256; xb = gx - 24; }
    else              { W = Wo; WT = WoT; NC = 256; xb = gx - 32; }
    int tx = threadIdx.x, ty = threadIdx.y;
    int x = xb * 32 + tx;
    int y0 = blockIdx.y * 32;
    #pragma unroll
    for (int j = 0; j < 4; j++)
        t[ty + j * 8][tx] = W[(size_t)(y0 + ty + j * 8) * NC + x];
    __syncthreads();
    #pragma unroll
    for (int j = 0; j < 4; j++)
        WT[(size_t)(xb * 32 + ty + j * 8) * 256 + y0 + tx] =
            f2bf(t[tx][ty + j * 8]);
}

// P2: mask -> bit-packed mbt [B*T][16]; word w bit c = mask[row][c*16+w]
__global__ __launch_bounds__(256) void packmask_k(const int* __restrict__ mask,
                                                  uint* __restrict__ mbt) {
    int idx = blockIdx.x * 256 + threadIdx.x;
    int row = idx >> 4, w = idx & 15;
    const int* mr = mask + (size_t)row * NN + w;
    uint u = 0;
    #pragma unroll
    for (int c = 0; c < 32; c++) u |= (uint)(mr[c * 16] != 0) << c;
    mbt[idx] = u;
}

// K0b: ctx = mean @ W_fixed; grid BB
__global__ __launch_bounds__(256) void ctx_mm_k(const float* __restrict__ partial,
                                                const float* __restrict__ Wf,
                                                float* __restrict__ ctx) {
    int b = blockIdx.x, d = threadIdx.x;
    __shared__ float ms[256];
    float s = 0.f;
    #pragma unroll
    for (int p = 0; p < 8; p++) s += partial[((size_t)b * 8 + p) * DD + d];
    ms[d] = s * (1.0f / NN);
    __syncthreads();
    float acc = 0.f;
    #pragma unroll 8
    for (int k = 0; k < 256; k++) acc += ms[k] * Wf[(size_t)k * DD + d];
    ctx[(size_t)b * DD + d] = acc;
}

// ---------------------------------------------------------------------------
// MFMA GEMM: C[M,256*?] = A[M,256](bf16) @ W via WT[NC][256] bf16.
// 1-D grid j: x = j&255 (row panel), y = j>>8 (col group).
// SPLIT=1: cols 0-255 -> gkT [bh][n][32] (per-head contiguous!);
//          256-511 -> vT [(bh)*32+dh][512]; 512-767 -> lk [r][256].
template <int GATHER, int BIAS, int SPLIT>
__global__ __launch_bounds__(256) void gemm_mfma_k(
    const ushort* __restrict__ A, const ushort* __restrict__ WT,
    ushort* __restrict__ O0, ushort* __restrict__ O1, ushort* __restrict__ O2,
    const float* __restrict__ bias, const int* __restrict__ gidx, int CPB) {
    int j = blockIdx.x;
    int bx = j & 255, by = j >> 8;
    int tid = threadIdx.x;
    int w = tid >> 6, l = tid & 63;
    int lo = l & 15, hi = l >> 4;
    int row0 = bx * 64 + w * 16;
    int arow = row0 + lo;
    const ushort* ap;
    if (GATHER) {
        int b = arow >> 9;
        int node = gidx[arow];
        ap = A + ((size_t)(b * NN + node)) * DD;
    } else {
        ap = A + (size_t)arow * DD;
    }
    bf16x8 af[8];
    #pragma unroll
    for (int ks = 0; ks < 8; ks++)
        af[ks] = *(const bf16x8*)(ap + ks * 32 + hi * 8);

    const f32x4 zero = {0.f, 0.f, 0.f, 0.f};
    for (int c = 0; c < CPB; c++) {
        int cg = by * CPB + c;
        int col = cg * 16 + lo;
        const ushort* bp = WT + (size_t)col * 256 + hi * 8;
        f32x4 acc = zero;
        #pragma unroll
        for (int ks = 0; ks < 8; ks++)
            acc = __builtin_amdgcn_mfma_f32_16x16x32_bf16(
                af[ks], *(const bf16x8*)(bp + ks * 32), acc, 0, 0, 0);
        float v[4];
        #pragma unroll
        for (int r = 0; r < 4; r++) {
            v[r] = acc[r];
            if (BIAS) v[r] += bias[(size_t)(row0 >> 9) * DD + col];
        }
        if (SPLIT == 0) {
            #pragma unroll
            for (int r = 0; r < 4; r++)
                O0[(size_t)(row0 + 4 * hi + r) * DD + col] = f2bf(v[r]);
        } else {
            int bb = row0 >> 9;
            if (col < 256) {
                // gkT: per-head contiguous [bh][n][32]
                int head = col >> 5, dh = col & 31;
                #pragma unroll
                for (int r = 0; r < 4; r++) {
                    int n = (row0 + 4 * hi + r) & (NN - 1);
                    O0[(((size_t)(bb * HH + head) * NN + n) << 5) + dh] = f2bf(v[r]);
                }
            } else if (col < 512) {
                int cc = col - 256;
                int bh = bb * HH + (cc >> 5);
                int dh = cc & 31;
                int n0 = (row0 + 4 * hi) & (NN - 1);
                ushort4 uv = {f2bf(v[0]), f2bf(v[1]), f2bf(v[2]), f2bf(v[3])};
                *(ushort4*)(O1 + ((size_t)bh * DH + dh) * NN + n0) = uv;
            } else {
                #pragma unroll
                for (int r = 0; r < 4; r++)
                    O2[(size_t)(row0 + 4 * hi + r) * 256 + (col - 512)] = f2bf(v[r]);
            }
        }
    }
}

// ---------------------------------------------------------------------------
// K3: LDS-staged swapped-operand MFMA attention.
// Block = (bh, half): stages K[512][32] and V^T[32][512] (both 32KB) into
// swizzled LDS once, then 4 q-chunks x 4 waves consume via ds_read_b128.
// Swapped QK^T (verified r7): lane(lo,hi) holds S^T[n=c*16+4hi+r][q=lo];
// packed e-values ARE the PV B-fragment; V n-permuted (n''=32p+8g+4s+r) so
// each PV A-fragment is ONE b128 read. No max subtraction (|s*sc|<~12).
__global__ __launch_bounds__(256) void attn7_k(
    const ushort* __restrict__ gq, const ushort* __restrict__ gkT,
    const ushort* __restrict__ vT, const uint* __restrict__ mbt,
    ushort* __restrict__ headsB) {
    int j = blockIdx.x;
    int bh = j & 255, half = j >> 8;
    int b = bh >> 3, h = bh & 7;
    int tid = threadIdx.x;
    int w = tid >> 6, l = tid & 63;
    int lo = l & 15, hi = l >> 4;

    __shared__ ushort Ks[16384];      // 32KB: rows n (64B), addr ^= ((n&7)<<4)
    __shared__ ushort Vs[16384];      // 32KB: rows dh (1KB), n-permuted, ^((dh&7)<<4)
    __shared__ ushort OT[4][16][40];  // 5KB transpose staging

    // ---- stage K: contiguous 32KB, swz on linear addr
    {
        const uint4* src = (const uint4*)(gkT + (size_t)bh * (NN * DH));
        #pragma unroll
        for (int i = 0; i < 8; i++) {
            int u = i * 256 + tid;          // 16B unit
            uint4 v = src[u];
            int G = u << 4;
            int a = G ^ (((G >> 6) & 7) << 4);
            *(uint4*)((char*)Ks + a) = v;
        }
    }
    // ---- stage V: global [dh][n] (n=32p+16s+4g+r) -> lds [dh][n''=32p+8g+4s+r]
    {
        const uint4* src = (const uint4*)(vT + (size_t)bh * (DH * NN));
        #pragma unroll
        for (int i = 0; i < 8; i++) {
            int u = i * 256 + tid;          // 16B unit: dh=u>>6, 8 shorts
            uint4 v = src[u];
            int dh = u >> 6;
            int n0 = (u & 63) << 3;         // = 32p + 16s + 8q
            int p = n0 >> 5, rem = n0 & 31;
            int s = rem >> 4, q = (rem >> 3) & 1;
            int na = 32 * p + 16 * q + 4 * s;  // dest n'' for first 4 (g=2q)
            int swz = (dh & 7) << 4;
            int a0 = ((dh << 10) + (na << 1)) ^ swz;
            int a1 = ((dh << 10) + (na << 1) + 16) ^ swz;  // g=2q+1 -> n''+8
            uint2 w0 = {v.x, v.y};
            uint2 w1 = {v.z, v.w};
            *(uint2*)((char*)Vs + a0) = w0;
            *(uint2*)((char*)Vs + a1) = w1;
        }
    }
    __syncthreads();

    const f32x4 zero = {0.f, 0.f, 0.f, 0.f};
    const float sc = 0.17677669529663687f;  // 1/sqrt(32)
    int q0 = half * 256;
    int kswz = (lo & 7) << 4;

    for (int qc2 = 0; qc2 < 4; qc2++) {
        int t0 = q0 + qc2 * 64 + w * 16;
        bf16x8 qf = *(const bf16x8*)(gq + ((size_t)(b * TT + t0 + lo)) * DD + h * DH + hi * 8);
        uint4 mq = *(const uint4*)(mbt + ((size_t)(b * TT + t0 + lo)) * 16 + 4 * hi);

        float sum = 0.f;
        f32x4 o0 = zero, o1 = zero;

        #pragma unroll
        for (int p = 0; p < 16; p++) {
            int n0 = 32 * p + lo;
            bf16x8 kf0 = *(const bf16x8*)((char*)Ks + ((n0 * 64 + hi * 16) ^ kswz));
            bf16x8 kf1 = *(const bf16x8*)((char*)Ks + (((n0 + 16) * 64 + hi * 16) ^ kswz));
            f32x4 s0 = __builtin_amdgcn_mfma_f32_16x16x32_bf16(kf0, qf, zero, 0, 0, 0);
            f32x4 s1 = __builtin_amdgcn_mfma_f32_16x16x32_bf16(kf1, qf, zero, 0, 0, 0);
            union { bf16x8 v; uint u[4]; } pf;
            {
                const int c = 2 * p;
                float e0 = ((mq.x >> c) & 1u) ? __expf(s0[0] * sc) : 0.f;
                float e1 = ((mq.y >> c) & 1u) ? __expf(s0[1] * sc) : 0.f;
                float e2 = ((mq.z >> c) & 1u) ? __expf(s0[2] * sc) : 0.f;
                float e3 = ((mq.w >> c) & 1u) ? __expf(s0[3] * sc) : 0.f;
                sum += (e0 + e1) + (e2 + e3);
                pf.u[0] = pk2(e0, e1);
                pf.u[1] = pk2(e2, e3);
            }
            {
                const int c = 2 * p + 1;
                float e0 = ((mq.x >> c) & 1u) ? __expf(s1[0] * sc) : 0.f;
                float e1 = ((mq.y >> c) & 1u) ? __expf(s1[1] * sc) : 0.f;
                float e2 = ((mq.z >> c) & 1u) ? __expf(s1[2] * sc) : 0.f;
                float e3 = ((mq.w >> c) & 1u) ? __expf(s1[3] * sc) : 0.f;
                sum += (e0 + e1) + (e2 + e3);
                pf.u[2] = pk2(e0, e1);
                pf.u[3] = pk2(e2, e3);
            }
            // PV A-fragments: one b128 each (n-permuted layout)
            int vo = (32 * p + 8 * hi) * 2;
            bf16x8 va0 = *(const bf16x8*)((char*)Vs + (((lo << 10) + vo) ^ kswz));
            bf16x8 va1 = *(const bf16x8*)((char*)Vs + ((((lo + 16) << 10) + vo) ^ kswz));
            o0 = __builtin_amdgcn_mfma_f32_16x16x32_bf16(va0, pf.v, o0, 0, 0, 0);
            o1 = __builtin_amdgcn_mfma_f32_16x16x32_bf16(va1, pf.v, o1, 0, 0, 0);
        }

        sum += __shfl_xor(sum, 16);
        sum += __shfl_xor(sum, 32);
        float inv = 1.0f / fmaxf(sum, 1e-30f);

        #pragma unroll
        for (int r = 0; r < 4; r++) {
            OT[w][lo][4 * hi + r] = f2bf(o0[r] * inv);
            OT[w][lo][16 + 4 * hi + r] = f2bf(o1[r] * inv);
        }
        bf16x8 ov = *(const bf16x8*)(&OT[w][lo][hi * 8]);
        *(bf16x8*)(headsB + ((size_t)(b * TT + t0 + lo)) * DD + h * DH + hi * 8) = ov;
    }
}

// ---------------------------------------------------------------------------
// K5: MFMA pointer logits + log_softmax with FIXED max = 10 (tanh bound).
// grid j: b = j&31, tc = j>>5.
__global__ __launch_bounds__(256) void logits4_k(
    const ushort* __restrict__ glimpse, const ushort* __restrict__ lk,
    const uint* __restrict__ mbt, float* __restrict__ out) {
    int j = blockIdx.x;  // B * T/16
    int b = j & 31;
    int t0 = (j >> 5) * 16;
    int tid = threadIdx.x;
    int w = tid >> 6, l = tid & 63;
    int lo = l & 15, hi = l >> 4;

    __shared__ float reds[4][16];

    bf16x8 af[8];
    const ushort* gb = glimpse + ((size_t)(b * TT + t0 + lo)) * DD + hi * 8;
    #pragma unroll
    for (int ks = 0; ks < 8; ks++) af[ks] = *(const bf16x8*)(gb + ks * 32);
    uint mw[4];
    #pragma unroll
    for (int r = 0; r < 4; r++)
        mw[r] = mbt[((size_t)(b * TT + t0 + 4 * hi + r)) * 16 + lo];

    const f32x4 zero = {0.f, 0.f, 0.f, 0.f};
    const ushort* lkb = lk + (size_t)b * NN * DD + hi * 8;
    float sum[4] = {0.f, 0.f, 0.f, 0.f};
    uint tu[16];
    #pragma unroll
    for (int cl = 0; cl < 8; cl++) {
        int c = w * 8 + cl;
        f32x4 acc = zero;
        const ushort* kr = lkb + (size_t)(c * 16 + lo) * DD;
        #pragma unroll
        for (int ks = 0; ks < 8; ks++)
            acc = __builtin_amdgcn_mfma_f32_16x16x32_bf16(
                af[ks], *(const bf16x8*)(kr + ks * 32), acc, 0, 0, 0);
        float t[4];
        #pragma unroll
        for (int r = 0; r < 4; r++) {
            t[r] = fast_tanh10(acc[r] * 0.0625f);
            sum[r] += ((mw[r] >> c) & 1u) ? __expf(t[r] - 10.f) : 0.f;
        }
        tu[2 * cl] = pk2(t[0], t[1]);
        tu[2 * cl + 1] = pk2(t[2], t[3]);
    }
    #pragma unroll
    for (int r = 0; r < 4; r++)
        #pragma unroll
        for (int o = 1; o < 16; o <<= 1) sum[r] += __shfl_xor(sum[r], o);
    if (lo == 0) {
        #pragma unroll
        for (int r = 0; r < 4; r++) reds[w][4 * hi + r] = sum[r];
    }
    __syncthreads();
    float lse[4];
    #pragma unroll
    for (int r = 0; r < 4; r++) {
        int row = 4 * hi + r;
        float s = reds[0][row] + reds[1][row] + reds[2][row] + reds[3][row];
        lse[r] = 10.f + __logf(fmaxf(s, 1e-37f));
    }

    #pragma unroll
    for (int cl = 0; cl < 8; cl++) {
        int c = w * 8 + cl;
        float v[4] = {ulo(tu[2 * cl]), uhi(tu[2 * cl]),
                      ulo(tu[2 * cl + 1]), uhi(tu[2 * cl + 1])};
        #pragma unroll
        for (int r = 0; r < 4; r++) {
            float ov = ((mw[r] >> c) & 1u) ? v[r] - lse[r] : NEG_INF - lse[r];
            out[((size_t)(b * TT + t0 + 4 * hi + r)) * NN + c * 16 + lo] = ov;
        }
    }
}

// ---------------------------------------------------------------------------
extern "C" void kernel_launch(void* const* d_in, const int* in_sizes, int n_in,
                              void* d_out, int out_size, void* d_ws,
                              size_t ws_size, hipStream_t stream) {
    const float* emb = (const float*)d_in[0];
    const int* cur   = (const int*)d_in[1];
    const int* mask  = (const int*)d_in[2];
    const float* Wn  = (const float*)d_in[3];
    const float* Wf  = (const float*)d_in[4];
    const float* Ws  = (const float*)d_in[5];
    const float* Wo  = (const float*)d_in[6];
    float* out = (float*)d_out;

    const size_t SLABE = (size_t)BB * NN * DD;
    ushort* embB     = (ushort*)d_ws;
    ushort* gkT      = embB + SLABE;     // [bh][n][32] per-head contiguous
    ushort* vT       = gkT + SLABE;      // [(bh)*32+dh][512]
    ushort* lkb      = vT + SLABE;
    ushort* gq       = lkb + SLABE;
    ushort* headsB   = gq + SLABE;
    ushort* glimpseB = headsB + SLABE;
    ushort* WnT      = glimpseB + SLABE;
    ushort* WsT      = WnT + 768 * 256;
    ushort* WoT      = WsT + 256 * 256;
    uint*   mbt      = (uint*)(WoT + 256 * 256);
    float*  ctx      = (float*)(mbt + (size_t)BB * TT * 16);
    float*  partial  = ctx + (size_t)BB * DD;

    // prep (fused)
    cvt_ctx_k<<<dim3(BB, 8), 256, 0, stream>>>(emb, embB, partial);
    twt_all_k<<<dim3(40, 8), dim3(32, 8), 0, stream>>>(Wn, Ws, Wo, WnT, WsT, WoT);
    packmask_k<<<BB * TT * 16 / 256, 256, 0, stream>>>(mask, mbt);
    ctx_mm_k<<<BB, 256, 0, stream>>>(partial, Wf, ctx);

    // K1: proj = emb @ W_node -> gkT / vT / lk
    gemm_mfma_k<0, 0, 1><<<3072, 256, 0, stream>>>(
        embB, WnT, gkT, vT, lkb, nullptr, nullptr, 4);
    // K2: glimpse_q = emb[cur] @ W_step + ctx -> gq
    gemm_mfma_k<1, 1, 0><<<1024, 256, 0, stream>>>(
        embB, WsT, gq, nullptr, nullptr, ctx, cur, 4);
    // K3: LDS-staged attention -> headsB
    attn7_k<<<512, 256, 0, stream>>>(gq, gkT, vT, mbt, headsB);
    // K4: glimpse = heads @ W_out
    gemm_mfma_k<0, 0, 0><<<1024, 256, 0, stream>>>(
        headsB, WoT, glimpseB, nullptr, nullptr, nullptr, nullptr, 4);
    // K5: pointer logits + log_softmax
    logits4_k<<<BB * TT / 16, 256, 0, stream>>>(glimpseB, lkb, mbt, out);
}

// Round 9
// 147.662 us; speedup vs baseline: 1.8262x; 1.4566x over previous
//
#include <hip/hip_runtime.h>
#include <hip/hip_bf16.h>

constexpr int BB = 32;    // batch
constexpr int TT = 512;   // decode steps
constexpr int NN = 512;   // nodes
constexpr int DD = 256;   // model dim
constexpr int HH = 8;     // heads
constexpr int DH = 32;    // head dim
#define NEG_INF (-1e9f)

typedef __attribute__((ext_vector_type(8))) short bf16x8;
typedef __attribute__((ext_vector_type(4))) float f32x4;

__device__ inline ushort f2bf(float x) {
    union { float f; unsigned u; } c; c.f = x;
    unsigned u = c.u + 0x7fffu + ((c.u >> 16) & 1u);  // RNE
    return (ushort)(u >> 16);
}
__device__ inline uint pk2(float a, float b) {
    return (uint)f2bf(a) | ((uint)f2bf(b) << 16);
}
__device__ inline float ulo(uint u) {
    union { uint u; float f; } c; c.u = u << 16; return c.f;
}
__device__ inline float uhi(uint u) {
    union { uint u; float f; } c; c.u = u & 0xffff0000u; return c.f;
}
__device__ inline float fast_tanh10(float x) {
    x = fminf(fmaxf(x, -20.f), 20.f);
    float e2 = __expf(2.f * x);
    return 10.f * (1.f - 2.f / (e2 + 1.f));
}

// ---------------------------------------------------------------------------
// P0': fused emb fp32->bf16 convert + per-(b,part) partial sums. grid (BB,8).
__global__ __launch_bounds__(256) void cvt_ctx_k(const float* __restrict__ emb,
                                                 ushort* __restrict__ embB,
                                                 float* __restrict__ partial) {
    int b = blockIdx.x, part = blockIdx.y, d = threadIdx.x;
    const float* eb = emb + ((size_t)b * NN + part * 64) * DD + d;
    ushort* ob = embB + ((size_t)b * NN + part * 64) * DD + d;
    float s = 0.f;
    #pragma unroll 4
    for (int i = 0; i < 64; i++) {
        float v = eb[(size_t)i * DD];
        s += v;
        ob[(size_t)i * DD] = f2bf(v);
    }
    partial[((size_t)b * 8 + part) * DD + d] = s;
}

// P1': all three weight transposes in one launch. grid (40, 8), block (32,8).
__global__ void twt_all_k(const float* __restrict__ Wn,
                          const float* __restrict__ Ws,
                          const float* __restrict__ Wo,
                          ushort* __restrict__ WnT, ushort* __restrict__ WsT,
                          ushort* __restrict__ WoT) {
    __shared__ float t[32][33];
    int gx = blockIdx.x;
    const float* W;
    ushort* WT;
    int NC, xb;
    if (gx < 24)      { W = Wn; WT = WnT; NC = 768; xb = gx; }
    else if (gx < 32) { W = Ws; WT = WsT; NC = 256; xb = gx - 24; }
    else              { W = Wo; WT = WoT; NC = 256; xb = gx - 32; }
    int tx = threadIdx.x, ty = threadIdx.y;
    int x = xb * 32 + tx;
    int y0 = blockIdx.y * 32;
    #pragma unroll
    for (int j = 0; j < 4; j++)
        t[ty + j * 8][tx] = W[(size_t)(y0 + ty + j * 8) * NC + x];
    __syncthreads();
    #pragma unroll
    for (int j = 0; j < 4; j++)
        WT[(size_t)(xb * 32 + ty + j * 8) * 256 + y0 + tx] =
            f2bf(t[tx][ty + j * 8]);
}

// P2: mask -> bit-packed mbt [B*T][16]; word w bit c = mask[row][c*16+w]
__global__ __launch_bounds__(256) void packmask_k(const int* __restrict__ mask,
                                                  uint* __restrict__ mbt) {
    int idx = blockIdx.x * 256 + threadIdx.x;
    int row = idx >> 4, w = idx & 15;
    const int* mr = mask + (size_t)row * NN + w;
    uint u = 0;
    #pragma unroll
    for (int c = 0; c < 32; c++) u |= (uint)(mr[c * 16] != 0) << c;
    mbt[idx] = u;
}

// K0b: ctx = mean @ W_fixed; grid BB
__global__ __launch_bounds__(256) void ctx_mm_k(const float* __restrict__ partial,
                                                const float* __restrict__ Wf,
                                                float* __restrict__ ctx) {
    int b = blockIdx.x, d = threadIdx.x;
    __shared__ float ms[256];
    float s = 0.f;
    #pragma unroll
    for (int p = 0; p < 8; p++) s += partial[((size_t)b * 8 + p) * DD + d];
    ms[d] = s * (1.0f / NN);
    __syncthreads();
    float acc = 0.f;
    #pragma unroll 8
    for (int k = 0; k < 256; k++) acc += ms[k] * Wf[(size_t)k * DD + d];
    ctx[(size_t)b * DD + d] = acc;
}

// ---------------------------------------------------------------------------
// LDS-staged MFMA GEMM: C[64rows x 64cols per block] = A[.,256] @ WT[col][256].
// Both tiles staged in XOR-swizzled LDS (byte ^= ((row&7)<<4), rule #21 pair);
// fragments via conflict-free ds_read_b128; 4 interleaved acc chains for ILP.
// 1-D grid j: bx = j&255 (row panel), by = j>>8 (64-col group).
// SPLIT=1: cols 0-255 -> gkT [bh][n][32]; 256-511 -> vT [(bh)*32+dh][512];
//          512-767 -> lk [r][256].
template <int GATHER, int BIAS, int SPLIT>
__global__ __launch_bounds__(256) void gemm2_k(
    const ushort* __restrict__ A, const ushort* __restrict__ WT,
    ushort* __restrict__ O0, ushort* __restrict__ O1, ushort* __restrict__ O2,
    const float* __restrict__ bias, const int* __restrict__ gidx) {
    int j = blockIdx.x;
    int bx = j & 255, by = j >> 8;
    int tid = threadIdx.x;
    int w = tid >> 6, l = tid & 63;
    int lo = l & 15, hi = l >> 4;
    int row0 = bx * 64;
    int col0 = by * 64;

    __shared__ ushort As[16384];  // 32KB: 64 rows x 512B, swz ((row&7)<<4)
    __shared__ ushort Bs[16384];  // 32KB: 64 cols x 512B, swz ((col&7)<<4)

    // stage A (coalesced; GATHER-aware)
    #pragma unroll
    for (int i = 0; i < 8; i++) {
        int u = i * 256 + tid;          // 16B unit
        int row = u >> 5, c16 = u & 31;
        int arow = row0 + row;
        const ushort* ap;
        if (GATHER) {
            int b = arow >> 9;
            ap = A + ((size_t)(b * NN + gidx[arow])) * DD;
        } else {
            ap = A + (size_t)arow * DD;
        }
        uint4 v = *(const uint4*)(ap + c16 * 8);
        *(uint4*)((char*)As + (((row << 9) + (c16 << 4)) ^ ((row & 7) << 4))) = v;
    }
    // stage B (coalesced, shared by all 4 waves)
    #pragma unroll
    for (int i = 0; i < 8; i++) {
        int u = i * 256 + tid;
        int col = u >> 5, c16 = u & 31;
        uint4 v = *(const uint4*)(WT + (size_t)(col0 + col) * 256 + c16 * 8);
        *(uint4*)((char*)Bs + (((col << 9) + (c16 << 4)) ^ ((col & 7) << 4))) = v;
    }
    __syncthreads();

    int swz = (lo & 7) << 4;
    // A fragments for this wave's 16 rows (row = w*16+lo)
    bf16x8 af[8];
    #pragma unroll
    for (int ks = 0; ks < 8; ks++)
        af[ks] = *(const bf16x8*)((char*)As +
            ((((w * 16 + lo) << 9) + (ks << 6) + (hi << 4)) ^ swz));

    const f32x4 zero = {0.f, 0.f, 0.f, 0.f};
    f32x4 acc[4] = {zero, zero, zero, zero};
    #pragma unroll
    for (int ks = 0; ks < 8; ks++) {
        #pragma unroll
        for (int c = 0; c < 4; c++) {
            bf16x8 bf = *(const bf16x8*)((char*)Bs +
                ((((c * 16 + lo) << 9) + (ks << 6) + (hi << 4)) ^ swz));
            acc[c] = __builtin_amdgcn_mfma_f32_16x16x32_bf16(af[ks], bf, acc[c], 0, 0, 0);
        }
    }

    int rw0 = row0 + w * 16;
    int bb = rw0 >> 9;
    #pragma unroll
    for (int c = 0; c < 4; c++) {
        int col = col0 + c * 16 + lo;
        float v[4];
        #pragma unroll
        for (int r = 0; r < 4; r++) {
            v[r] = acc[c][r];
            if (BIAS) v[r] += bias[(size_t)bb * DD + col];
        }
        if (SPLIT == 0) {
            #pragma unroll
            for (int r = 0; r < 4; r++)
                O0[(size_t)(rw0 + 4 * hi + r) * DD + col] = f2bf(v[r]);
        } else {
            if (col < 256) {
                int head = col >> 5, dh = col & 31;
                #pragma unroll
                for (int r = 0; r < 4; r++) {
                    int n = (rw0 + 4 * hi + r) & (NN - 1);
                    O0[(((size_t)(bb * HH + head) * NN + n) << 5) + dh] = f2bf(v[r]);
                }
            } else if (col < 512) {
                int cc = col - 256;
                int bh = bb * HH + (cc >> 5);
                int dh = cc & 31;
                int n0 = (rw0 + 4 * hi) & (NN - 1);
                ushort4 uv = {f2bf(v[0]), f2bf(v[1]), f2bf(v[2]), f2bf(v[3])};
                *(ushort4*)(O1 + ((size_t)bh * DH + dh) * NN + n0) = uv;
            } else {
                #pragma unroll
                for (int r = 0; r < 4; r++)
                    O2[(size_t)(rw0 + 4 * hi + r) * 256 + (col - 512)] = f2bf(v[r]);
            }
        }
    }
}

// ---------------------------------------------------------------------------
// K3: LDS-staged swapped-operand MFMA attention (verified r8).
__global__ __launch_bounds__(256) void attn7_k(
    const ushort* __restrict__ gq, const ushort* __restrict__ gkT,
    const ushort* __restrict__ vT, const uint* __restrict__ mbt,
    ushort* __restrict__ headsB) {
    int j = blockIdx.x;
    int bh = j & 255, half = j >> 8;
    int b = bh >> 3, h = bh & 7;
    int tid = threadIdx.x;
    int w = tid >> 6, l = tid & 63;
    int lo = l & 15, hi = l >> 4;

    __shared__ ushort Ks[16384];      // 32KB: rows n (64B), addr ^= ((n&7)<<4)
    __shared__ ushort Vs[16384];      // 32KB: rows dh (1KB), n-permuted, ^((dh&7)<<4)
    __shared__ ushort OT[4][16][40];  // 5KB transpose staging

    {
        const uint4* src = (const uint4*)(gkT + (size_t)bh * (NN * DH));
        #pragma unroll
        for (int i = 0; i < 8; i++) {
            int u = i * 256 + tid;
            uint4 v = src[u];
            int G = u << 4;
            int a = G ^ (((G >> 6) & 7) << 4);
            *(uint4*)((char*)Ks + a) = v;
        }
    }
    {
        const uint4* src = (const uint4*)(vT + (size_t)bh * (DH * NN));
        #pragma unroll
        for (int i = 0; i < 8; i++) {
            int u = i * 256 + tid;
            uint4 v = src[u];
            int dh = u >> 6;
            int n0 = (u & 63) << 3;
            int p = n0 >> 5, rem = n0 & 31;
            int s = rem >> 4, q = (rem >> 3) & 1;
            int na = 32 * p + 16 * q + 4 * s;
            int swz = (dh & 7) << 4;
            int a0 = ((dh << 10) + (na << 1)) ^ swz;
            int a1 = ((dh << 10) + (na << 1) + 16) ^ swz;
            uint2 w0 = {v.x, v.y};
            uint2 w1 = {v.z, v.w};
            *(uint2*)((char*)Vs + a0) = w0;
            *(uint2*)((char*)Vs + a1) = w1;
        }
    }
    __syncthreads();

    const f32x4 zero = {0.f, 0.f, 0.f, 0.f};
    const float sc = 0.17677669529663687f;  // 1/sqrt(32)
    int q0 = half * 256;
    int kswz = (lo & 7) << 4;

    for (int qc2 = 0; qc2 < 4; qc2++) {
        int t0 = q0 + qc2 * 64 + w * 16;
        bf16x8 qf = *(const bf16x8*)(gq + ((size_t)(b * TT + t0 + lo)) * DD + h * DH + hi * 8);
        uint4 mq = *(const uint4*)(mbt + ((size_t)(b * TT + t0 + lo)) * 16 + 4 * hi);

        float sum = 0.f;
        f32x4 o0 = zero, o1 = zero;

        #pragma unroll
        for (int p = 0; p < 16; p++) {
            int n0 = 32 * p + lo;
            bf16x8 kf0 = *(const bf16x8*)((char*)Ks + ((n0 * 64 + hi * 16) ^ kswz));
            bf16x8 kf1 = *(const bf16x8*)((char*)Ks + (((n0 + 16) * 64 + hi * 16) ^ kswz));
            f32x4 s0 = __builtin_amdgcn_mfma_f32_16x16x32_bf16(kf0, qf, zero, 0, 0, 0);
            f32x4 s1 = __builtin_amdgcn_mfma_f32_16x16x32_bf16(kf1, qf, zero, 0, 0, 0);
            union { bf16x8 v; uint u[4]; } pf;
            {
                const int c = 2 * p;
                float e0 = ((mq.x >> c) & 1u) ? __expf(s0[0] * sc) : 0.f;
                float e1 = ((mq.y >> c) & 1u) ? __expf(s0[1] * sc) : 0.f;
                float e2 = ((mq.z >> c) & 1u) ? __expf(s0[2] * sc) : 0.f;
                float e3 = ((mq.w >> c) & 1u) ? __expf(s0[3] * sc) : 0.f;
                sum += (e0 + e1) + (e2 + e3);
                pf.u[0] = pk2(e0, e1);
                pf.u[1] = pk2(e2, e3);
            }
            {
                const int c = 2 * p + 1;
                float e0 = ((mq.x >> c) & 1u) ? __expf(s1[0] * sc) : 0.f;
                float e1 = ((mq.y >> c) & 1u) ? __expf(s1[1] * sc) : 0.f;
                float e2 = ((mq.z >> c) & 1u) ? __expf(s1[2] * sc) : 0.f;
                float e3 = ((mq.w >> c) & 1u) ? __expf(s1[3] * sc) : 0.f;
                sum += (e0 + e1) + (e2 + e3);
                pf.u[2] = pk2(e0, e1);
                pf.u[3] = pk2(e2, e3);
            }
            int vo = (32 * p + 8 * hi) * 2;
            bf16x8 va0 = *(const bf16x8*)((char*)Vs + (((lo << 10) + vo) ^ kswz));
            bf16x8 va1 = *(const bf16x8*)((char*)Vs + ((((lo + 16) << 10) + vo) ^ kswz));
            o0 = __builtin_amdgcn_mfma_f32_16x16x32_bf16(va0, pf.v, o0, 0, 0, 0);
            o1 = __builtin_amdgcn_mfma_f32_16x16x32_bf16(va1, pf.v, o1, 0, 0, 0);
        }

        sum += __shfl_xor(sum, 16);
        sum += __shfl_xor(sum, 32);
        float inv = 1.0f / fmaxf(sum, 1e-30f);

        #pragma unroll
        for (int r = 0; r < 4; r++) {
            OT[w][lo][4 * hi + r] = f2bf(o0[r] * inv);
            OT[w][lo][16 + 4 * hi + r] = f2bf(o1[r] * inv);
        }
        bf16x8 ov = *(const bf16x8*)(&OT[w][lo][hi * 8]);
        *(bf16x8*)(headsB + ((size_t)(b * TT + t0 + lo)) * DD + h * DH + hi * 8) = ov;
    }
}

// ---------------------------------------------------------------------------
// K5: MFMA pointer logits + log_softmax with FIXED max = 10 (tanh bound).
__global__ __launch_bounds__(256) void logits4_k(
    const ushort* __restrict__ glimpse, const ushort* __restrict__ lk,
    const uint* __restrict__ mbt, float* __restrict__ out) {
    int j = blockIdx.x;  // B * T/16
    int b = j & 31;
    int t0 = (j >> 5) * 16;
    int tid = threadIdx.x;
    int w = tid >> 6, l = tid & 63;
    int lo = l & 15, hi = l >> 4;

    __shared__ float reds[4][16];

    bf16x8 af[8];
    const ushort* gb = glimpse + ((size_t)(b * TT + t0 + lo)) * DD + hi * 8;
    #pragma unroll
    for (int ks = 0; ks < 8; ks++) af[ks] = *(const bf16x8*)(gb + ks * 32);
    uint mw[4];
    #pragma unroll
    for (int r = 0; r < 4; r++)
        mw[r] = mbt[((size_t)(b * TT + t0 + 4 * hi + r)) * 16 + lo];

    const f32x4 zero = {0.f, 0.f, 0.f, 0.f};
    const ushort* lkb = lk + (size_t)b * NN * DD + hi * 8;
    float sum[4] = {0.f, 0.f, 0.f, 0.f};
    uint tu[16];
    #pragma unroll
    for (int cl = 0; cl < 8; cl++) {
        int c = w * 8 + cl;
        f32x4 acc = zero;
        const ushort* kr = lkb + (size_t)(c * 16 + lo) * DD;
        #pragma unroll
        for (int ks = 0; ks < 8; ks++)
            acc = __builtin_amdgcn_mfma_f32_16x16x32_bf16(
                af[ks], *(const bf16x8*)(kr + ks * 32), acc, 0, 0, 0);
        float t[4];
        #pragma unroll
        for (int r = 0; r < 4; r++) {
            t[r] = fast_tanh10(acc[r] * 0.0625f);
            sum[r] += ((mw[r] >> c) & 1u) ? __expf(t[r] - 10.f) : 0.f;
        }
        tu[2 * cl] = pk2(t[0], t[1]);
        tu[2 * cl + 1] = pk2(t[2], t[3]);
    }
    #pragma unroll
    for (int r = 0; r < 4; r++)
        #pragma unroll
        for (int o = 1; o < 16; o <<= 1) sum[r] += __shfl_xor(sum[r], o);
    if (lo == 0) {
        #pragma unroll
        for (int r = 0; r < 4; r++) reds[w][4 * hi + r] = sum[r];
    }
    __syncthreads();
    float lse[4];
    #pragma unroll
    for (int r = 0; r < 4; r++) {
        int row = 4 * hi + r;
        float s = reds[0][row] + reds[1][row] + reds[2][row] + reds[3][row];
        lse[r] = 10.f + __logf(fmaxf(s, 1e-37f));
    }

    #pragma unroll
    for (int cl = 0; cl < 8; cl++) {
        int c = w * 8 + cl;
        float v[4] = {ulo(tu[2 * cl]), uhi(tu[2 * cl]),
                      ulo(tu[2 * cl + 1]), uhi(tu[2 * cl + 1])};
        #pragma unroll
        for (int r = 0; r < 4; r++) {
            float ov = ((mw[r] >> c) & 1u) ? v[r] - lse[r] : NEG_INF - lse[r];
            out[((size_t)(b * TT + t0 + 4 * hi + r)) * NN + c * 16 + lo] = ov;
        }
    }
}

// ---------------------------------------------------------------------------
extern "C" void kernel_launch(void* const* d_in, const int* in_sizes, int n_in,
                              void* d_out, int out_size, void* d_ws,
                              size_t ws_size, hipStream_t stream) {
    const float* emb = (const float*)d_in[0];
    const int* cur   = (const int*)d_in[1];
    const int* mask  = (const int*)d_in[2];
    const float* Wn  = (const float*)d_in[3];
    const float* Wf  = (const float*)d_in[4];
    const float* Ws  = (const float*)d_in[5];
    const float* Wo  = (const float*)d_in[6];
    float* out = (float*)d_out;

    const size_t SLABE = (size_t)BB * NN * DD;
    ushort* embB     = (ushort*)d_ws;
    ushort* gkT      = embB + SLABE;     // [bh][n][32] per-head contiguous
    ushort* vT       = gkT + SLABE;      // [(bh)*32+dh][512]
    ushort* lkb      = vT + SLABE;
    ushort* gq       = lkb + SLABE;
    ushort* headsB   = gq + SLABE;
    ushort* glimpseB = headsB + SLABE;
    ushort* WnT      = glimpseB + SLABE;
    ushort* WsT      = WnT + 768 * 256;
    ushort* WoT      = WsT + 256 * 256;
    uint*   mbt      = (uint*)(WoT + 256 * 256);
    float*  ctx      = (float*)(mbt + (size_t)BB * TT * 16);
    float*  partial  = ctx + (size_t)BB * DD;

    // prep (fused)
    cvt_ctx_k<<<dim3(BB, 8), 256, 0, stream>>>(emb, embB, partial);
    twt_all_k<<<dim3(40, 8), dim3(32, 8), 0, stream>>>(Wn, Ws, Wo, WnT, WsT, WoT);
    packmask_k<<<BB * TT * 16 / 256, 256, 0, stream>>>(mask, mbt);
    ctx_mm_k<<<BB, 256, 0, stream>>>(partial, Wf, ctx);

    // K1: proj = emb @ W_node -> gkT / vT / lk
    gemm2_k<0, 0, 1><<<3072, 256, 0, stream>>>(
        embB, WnT, gkT, vT, lkb, nullptr, nullptr);
    // K2: glimpse_q = emb[cur] @ W_step + ctx -> gq
    gemm2_k<1, 1, 0><<<1024, 256, 0, stream>>>(
        embB, WsT, gq, nullptr, nullptr, ctx, cur);
    // K3: LDS-staged attention -> headsB
    attn7_k<<<512, 256, 0, stream>>>(gq, gkT, vT, mbt, headsB);
    // K4: glimpse = heads @ W_out
    gemm2_k<0, 0, 0><<<1024, 256, 0, stream>>>(
        headsB, WoT, glimpseB, nullptr, nullptr, nullptr, nullptr);
    // K5: pointer logits + log_softmax
    logits4_k<<<BB * TT / 16, 256, 0, stream>>>(glimpseB, lkb, mbt, out);
}

// Round 10
// 129.830 us; speedup vs baseline: 2.0770x; 1.1373x over previous
//
#include <hip/hip_runtime.h>
#include <hip/hip_bf16.h>

constexpr int BB = 32;    // batch
constexpr int TT = 512;   // decode steps
constexpr int NN = 512;   // nodes
constexpr int DD = 256;   // model dim
constexpr int HH = 8;     // heads
constexpr int DH = 32;    // head dim
#define NEG_INF (-1e9f)

typedef __attribute__((ext_vector_type(8))) short bf16x8;
typedef __attribute__((ext_vector_type(4))) float f32x4;

__device__ inline ushort f2bf(float x) {
    union { float f; unsigned u; } c; c.f = x;
    unsigned u = c.u + 0x7fffu + ((c.u >> 16) & 1u);  // RNE
    return (ushort)(u >> 16);
}
__device__ inline uint pk2(float a, float b) {
    return (uint)f2bf(a) | ((uint)f2bf(b) << 16);
}
// truncating pack: (lo>>16)|(hi&0xffff0000) == v_perm_b32(hi, lo, 0x07060302)
__device__ inline uint pk2t(float a, float b) {
    return __builtin_amdgcn_perm(__float_as_uint(b), __float_as_uint(a),
                                 0x07060302u);
}
__device__ inline float ulo(uint u) {
    union { uint u; float f; } c; c.u = u << 16; return c.f;
}
__device__ inline float uhi(uint u) {
    union { uint u; float f; } c; c.u = u & 0xffff0000u; return c.f;
}
__device__ inline float fast_tanh10(float x) {
    x = fminf(fmaxf(x, -20.f), 20.f);
    float e2 = __expf(2.f * x);
    return 10.f * (1.f - 2.f / (e2 + 1.f));
}

// ---------------------------------------------------------------------------
// prep_all: block-ranged fusion of
//   [0,256)     cvt_ctx: emb f32->bf16 + partial sums (b = j>>3, part = j&7)
//   [256,576)   twt: 3 weight transposes (flattened 2D block)
//   [576,1600)  packmask: mask -> bit-packed mbt [B*T][16]
__global__ __launch_bounds__(256) void prep_all_k(
    const float* __restrict__ emb, ushort* __restrict__ embB,
    float* __restrict__ partial, const float* __restrict__ Wn,
    const float* __restrict__ Ws, const float* __restrict__ Wo,
    ushort* __restrict__ WnT, ushort* __restrict__ WsT,
    ushort* __restrict__ WoT, const int* __restrict__ mask,
    uint* __restrict__ mbt) {
    int j = blockIdx.x;
    int tid = threadIdx.x;
    if (j < 256) {
        int b = j >> 3, part = j & 7, d = tid;
        const float* eb = emb + ((size_t)b * NN + part * 64) * DD + d;
        ushort* ob = embB + ((size_t)b * NN + part * 64) * DD + d;
        float s = 0.f;
        #pragma unroll 4
        for (int i = 0; i < 64; i++) {
            float v = eb[(size_t)i * DD];
            s += v;
            ob[(size_t)i * DD] = f2bf(v);
        }
        partial[((size_t)b * 8 + part) * DD + d] = s;
    } else if (j < 576) {
        __shared__ float t[32][33];
        int g = j - 256;
        int gx = g % 40, gy = g / 40;
        const float* W;
        ushort* WT;
        int NC, xb;
        if (gx < 24)      { W = Wn; WT = WnT; NC = 768; xb = gx; }
        else if (gx < 32) { W = Ws; WT = WsT; NC = 256; xb = gx - 24; }
        else              { W = Wo; WT = WoT; NC = 256; xb = gx - 32; }
        int tx = tid & 31, ty = tid >> 5;
        int x = xb * 32 + tx;
        int y0 = gy * 32;
        #pragma unroll
        for (int i = 0; i < 4; i++)
            t[ty + i * 8][tx] = W[(size_t)(y0 + ty + i * 8) * NC + x];
        __syncthreads();
        #pragma unroll
        for (int i = 0; i < 4; i++)
            WT[(size_t)(xb * 32 + ty + i * 8) * 256 + y0 + tx] =
                f2bf(t[tx][ty + i * 8]);
    } else {
        int idx = (j - 576) * 256 + tid;
        int row = idx >> 4, w = idx & 15;
        const int* mr = mask + (size_t)row * NN + w;
        uint u = 0;
        #pragma unroll
        for (int c = 0; c < 32; c++) u |= (uint)(mr[c * 16] != 0) << c;
        mbt[idx] = u;
    }
}

// ctx = mean @ W_fixed; grid BB
__global__ __launch_bounds__(256) void ctx_mm_k(const float* __restrict__ partial,
                                                const float* __restrict__ Wf,
                                                float* __restrict__ ctx) {
    int b = blockIdx.x, d = threadIdx.x;
    __shared__ float ms[256];
    float s = 0.f;
    #pragma unroll
    for (int p = 0; p < 8; p++) s += partial[((size_t)b * 8 + p) * DD + d];
    ms[d] = s * (1.0f / NN);
    __syncthreads();
    float acc = 0.f;
    #pragma unroll 8
    for (int k = 0; k < 256; k++) acc += ms[k] * Wf[(size_t)k * DD + d];
    ctx[(size_t)b * DD + d] = acc;
}

// ---------------------------------------------------------------------------
// gemm12: K1 (j<3072: proj = emb @ Wn -> gkT/vTp/lk) and
//         K2 (j>=3072: gq = emb[cur] @ Ws + ctx) in one dispatch.
// LDS-staged both tiles, swizzle byte ^= ((row&7)<<4); 4 acc chains.
// vTp written PRE-PERMUTED: 4-group m=(n>>2): p=m>>3,s=(m>>2)&1,g=m&3 ->
// m''=8p+2g+s, so attn's V staging is a linear copy.
__global__ __launch_bounds__(256) void gemm12_k(
    const ushort* __restrict__ embB, const ushort* __restrict__ WnT,
    const ushort* __restrict__ WsT, ushort* __restrict__ gkT,
    ushort* __restrict__ vTp, ushort* __restrict__ lkb,
    ushort* __restrict__ gq, const float* __restrict__ ctx,
    const int* __restrict__ cur) {
    int j = blockIdx.x;
    bool k2 = j >= 3072;
    int jj = k2 ? j - 3072 : j;
    int bx = jj & 255, by = jj >> 8;
    int tid = threadIdx.x;
    int w = tid >> 6, l = tid & 63;
    int lo = l & 15, hi = l >> 4;
    int row0 = bx * 64;
    int col0 = by * 64;

    __shared__ ushort As[16384];
    __shared__ ushort Bs[16384];

    #pragma unroll
    for (int i = 0; i < 8; i++) {
        int u = i * 256 + tid;
        int row = u >> 5, c16 = u & 31;
        int arow = row0 + row;
        const ushort* ap;
        if (k2) {
            int b = arow >> 9;
            ap = embB + ((size_t)(b * NN + cur[arow])) * DD;
        } else {
            ap = embB + (size_t)arow * DD;
        }
        uint4 v = *(const uint4*)(ap + c16 * 8);
        *(uint4*)((char*)As + (((row << 9) + (c16 << 4)) ^ ((row & 7) << 4))) = v;
    }
    const ushort* WT = k2 ? WsT : WnT;
    #pragma unroll
    for (int i = 0; i < 8; i++) {
        int u = i * 256 + tid;
        int col = u >> 5, c16 = u & 31;
        uint4 v = *(const uint4*)(WT + (size_t)(col0 + col) * 256 + c16 * 8);
        *(uint4*)((char*)Bs + (((col << 9) + (c16 << 4)) ^ ((col & 7) << 4))) = v;
    }
    __syncthreads();

    int swz = (lo & 7) << 4;
    bf16x8 af[8];
    #pragma unroll
    for (int ks = 0; ks < 8; ks++)
        af[ks] = *(const bf16x8*)((char*)As +
            ((((w * 16 + lo) << 9) + (ks << 6) + (hi << 4)) ^ swz));

    const f32x4 zero = {0.f, 0.f, 0.f, 0.f};
    f32x4 acc[4] = {zero, zero, zero, zero};
    #pragma unroll
    for (int ks = 0; ks < 8; ks++) {
        #pragma unroll
        for (int c = 0; c < 4; c++) {
            bf16x8 bf = *(const bf16x8*)((char*)Bs +
                ((((c * 16 + lo) << 9) + (ks << 6) + (hi << 4)) ^ swz));
            acc[c] = __builtin_amdgcn_mfma_f32_16x16x32_bf16(af[ks], bf, acc[c], 0, 0, 0);
        }
    }

    int rw0 = row0 + w * 16;
    int bb = rw0 >> 9;
    #pragma unroll
    for (int c = 0; c < 4; c++) {
        int col = col0 + c * 16 + lo;
        float v[4];
        #pragma unroll
        for (int r = 0; r < 4; r++) v[r] = acc[c][r];
        if (k2) {
            #pragma unroll
            for (int r = 0; r < 4; r++) {
                v[r] += ctx[(size_t)bb * DD + col];
                gq[(size_t)(rw0 + 4 * hi + r) * DD + col] = f2bf(v[r]);
            }
        } else {
            if (col < 256) {
                int head = col >> 5, dh = col & 31;
                #pragma unroll
                for (int r = 0; r < 4; r++) {
                    int n = (rw0 + 4 * hi + r) & (NN - 1);
                    gkT[(((size_t)(bb * HH + head) * NN + n) << 5) + dh] = f2bf(v[r]);
                }
            } else if (col < 512) {
                int cc = col - 256;
                int bhv = bb * HH + (cc >> 5);
                int dh = cc & 31;
                int n0 = (rw0 + 4 * hi) & (NN - 1);
                int m = n0 >> 2;
                int p_ = m >> 3, s_ = (m >> 2) & 1, g_ = m & 3;
                int n0p = (8 * p_ + 2 * g_ + s_) << 2;
                ushort4 uv = {f2bf(v[0]), f2bf(v[1]), f2bf(v[2]), f2bf(v[3])};
                *(ushort4*)(vTp + ((size_t)bhv * DH + dh) * NN + n0p) = uv;
            } else {
                #pragma unroll
                for (int r = 0; r < 4; r++)
                    lkb[(size_t)(rw0 + 4 * hi + r) * 256 + (col - 512)] = f2bf(v[r]);
            }
        }
    }
}

// ---------------------------------------------------------------------------
// K4: glimpse = heads @ W_out (LDS-staged GEMM, verified r9)
__global__ __launch_bounds__(256) void gemm4_k(
    const ushort* __restrict__ A, const ushort* __restrict__ WT,
    ushort* __restrict__ O0) {
    int j = blockIdx.x;
    int bx = j & 255, by = j >> 8;
    int tid = threadIdx.x;
    int w = tid >> 6, l = tid & 63;
    int lo = l & 15, hi = l >> 4;
    int row0 = bx * 64;
    int col0 = by * 64;

    __shared__ ushort As[16384];
    __shared__ ushort Bs[16384];

    #pragma unroll
    for (int i = 0; i < 8; i++) {
        int u = i * 256 + tid;
        int row = u >> 5, c16 = u & 31;
        uint4 v = *(const uint4*)(A + (size_t)(row0 + row) * DD + c16 * 8);
        *(uint4*)((char*)As + (((row << 9) + (c16 << 4)) ^ ((row & 7) << 4))) = v;
    }
    #pragma unroll
    for (int i = 0; i < 8; i++) {
        int u = i * 256 + tid;
        int col = u >> 5, c16 = u & 31;
        uint4 v = *(const uint4*)(WT + (size_t)(col0 + col) * 256 + c16 * 8);
        *(uint4*)((char*)Bs + (((col << 9) + (c16 << 4)) ^ ((col & 7) << 4))) = v;
    }
    __syncthreads();

    int swz = (lo & 7) << 4;
    bf16x8 af[8];
    #pragma unroll
    for (int ks = 0; ks < 8; ks++)
        af[ks] = *(const bf16x8*)((char*)As +
            ((((w * 16 + lo) << 9) + (ks << 6) + (hi << 4)) ^ swz));

    const f32x4 zero = {0.f, 0.f, 0.f, 0.f};
    f32x4 acc[4] = {zero, zero, zero, zero};
    #pragma unroll
    for (int ks = 0; ks < 8; ks++) {
        #pragma unroll
        for (int c = 0; c < 4; c++) {
            bf16x8 bf = *(const bf16x8*)((char*)Bs +
                ((((c * 16 + lo) << 9) + (ks << 6) + (hi << 4)) ^ swz));
            acc[c] = __builtin_amdgcn_mfma_f32_16x16x32_bf16(af[ks], bf, acc[c], 0, 0, 0);
        }
    }
    int rw0 = row0 + w * 16;
    #pragma unroll
    for (int c = 0; c < 4; c++) {
        int col = col0 + c * 16 + lo;
        #pragma unroll
        for (int r = 0; r < 4; r++)
            O0[(size_t)(rw0 + 4 * hi + r) * DD + col] = f2bf(acc[c][r]);
    }
}

// ---------------------------------------------------------------------------
// K3: LDS-staged swapped-operand attention (r8/r9 verified layout) with
// (a) linear V staging (vTp pre-permuted), (b) v_perm truncating P pack,
// (c) denominator via mfma(ones, pf) -> no scalar sum adds, no shfl.
__global__ __launch_bounds__(256) void attn8_k(
    const ushort* __restrict__ gq, const ushort* __restrict__ gkT,
    const ushort* __restrict__ vTp, const uint* __restrict__ mbt,
    ushort* __restrict__ headsB) {
    int j = blockIdx.x;
    int bh = j & 255, half = j >> 8;
    int b = bh >> 3, h = bh & 7;
    int tid = threadIdx.x;
    int w = tid >> 6, l = tid & 63;
    int lo = l & 15, hi = l >> 4;

    __shared__ ushort Ks[16384];      // rows n (64B), byte ^= ((n&7)<<4)
    __shared__ ushort Vs[16384];      // rows dh (1KB), pre-permuted n'', ^((dh&7)<<4)
    __shared__ ushort OT[4][16][40];

    {
        const uint4* src = (const uint4*)(gkT + (size_t)bh * (NN * DH));
        #pragma unroll
        for (int i = 0; i < 8; i++) {
            int u = i * 256 + tid;
            uint4 v = src[u];
            int G = u << 4;
            int a = G ^ (((G >> 6) & 7) << 4);
            *(uint4*)((char*)Ks + a) = v;
        }
    }
    {
        const uint4* src = (const uint4*)(vTp + (size_t)bh * (DH * NN));
        #pragma unroll
        for (int i = 0; i < 8; i++) {
            int u = i * 256 + tid;
            uint4 v = src[u];
            int G = u << 4;
            int a = G ^ (((G >> 10) & 7) << 4);
            *(uint4*)((char*)Vs + a) = v;
        }
    }
    __syncthreads();

    const f32x4 zero = {0.f, 0.f, 0.f, 0.f};
    const bf16x8 ones = {(short)0x3F80, (short)0x3F80, (short)0x3F80,
                         (short)0x3F80, (short)0x3F80, (short)0x3F80,
                         (short)0x3F80, (short)0x3F80};
    const float sc = 0.17677669529663687f;  // 1/sqrt(32)
    int q0 = half * 256;
    int kswz = (lo & 7) << 4;

    for (int qc2 = 0; qc2 < 4; qc2++) {
        int t0 = q0 + qc2 * 64 + w * 16;
        bf16x8 qf = *(const bf16x8*)(gq + ((size_t)(b * TT + t0 + lo)) * DD + h * DH + hi * 8);
        uint4 mq = *(const uint4*)(mbt + ((size_t)(b * TT + t0 + lo)) * 16 + 4 * hi);

        f32x4 o0 = zero, o1 = zero, osum = zero;

        #pragma unroll
        for (int p = 0; p < 16; p++) {
            int n0 = 32 * p + lo;
            bf16x8 kf0 = *(const bf16x8*)((char*)Ks + ((n0 * 64 + hi * 16) ^ kswz));
            bf16x8 kf1 = *(const bf16x8*)((char*)Ks + (((n0 + 16) * 64 + hi * 16) ^ kswz));
            f32x4 s0 = __builtin_amdgcn_mfma_f32_16x16x32_bf16(kf0, qf, zero, 0, 0, 0);
            f32x4 s1 = __builtin_amdgcn_mfma_f32_16x16x32_bf16(kf1, qf, zero, 0, 0, 0);
            union { bf16x8 v; uint u[4]; } pf;
            {
                const int c = 2 * p;
                float e0 = ((mq.x >> c) & 1u) ? __expf(s0[0] * sc) : 0.f;
                float e1 = ((mq.y >> c) & 1u) ? __expf(s0[1] * sc) : 0.f;
                float e2 = ((mq.z >> c) & 1u) ? __expf(s0[2] * sc) : 0.f;
                float e3 = ((mq.w >> c) & 1u) ? __expf(s0[3] * sc) : 0.f;
                pf.u[0] = pk2t(e0, e1);
                pf.u[1] = pk2t(e2, e3);
            }
            {
                const int c = 2 * p + 1;
                float e0 = ((mq.x >> c) & 1u) ? __expf(s1[0] * sc) : 0.f;
                float e1 = ((mq.y >> c) & 1u) ? __expf(s1[1] * sc) : 0.f;
                float e2 = ((mq.z >> c) & 1u) ? __expf(s1[2] * sc) : 0.f;
                float e3 = ((mq.w >> c) & 1u) ? __expf(s1[3] * sc) : 0.f;
                pf.u[2] = pk2t(e0, e1);
                pf.u[3] = pk2t(e2, e3);
            }
            int vo = (32 * p + 8 * hi) * 2;
            bf16x8 va0 = *(const bf16x8*)((char*)Vs + (((lo << 10) + vo) ^ kswz));
            bf16x8 va1 = *(const bf16x8*)((char*)Vs + ((((lo + 16) << 10) + vo) ^ kswz));
            o0 = __builtin_amdgcn_mfma_f32_16x16x32_bf16(va0, pf.v, o0, 0, 0, 0);
            o1 = __builtin_amdgcn_mfma_f32_16x16x32_bf16(va1, pf.v, o1, 0, 0, 0);
            osum = __builtin_amdgcn_mfma_f32_16x16x32_bf16(ones, pf.v, osum, 0, 0, 0);
        }

        // every lane's osum rows are identical = sum over all 512 keys for q=lo
        float inv = 1.0f / fmaxf(osum[0], 1e-30f);

        #pragma unroll
        for (int r = 0; r < 4; r++) {
            OT[w][lo][4 * hi + r] = (ushort)(__float_as_uint(o0[r] * inv) >> 16);
            OT[w][lo][16 + 4 * hi + r] = (ushort)(__float_as_uint(o1[r] * inv) >> 16);
        }
        bf16x8 ov = *(const bf16x8*)(&OT[w][lo][hi * 8]);
        *(bf16x8*)(headsB + ((size_t)(b * TT + t0 + lo)) * DD + h * DH + hi * 8) = ov;
    }
}

// ---------------------------------------------------------------------------
// K5: LDS-staged pointer logits + log_softmax (fixed max = 10).
// Per block (b, 16 t-rows): 8 stage-iters of 64 lk rows (32KB swizzled);
// wave w computes chunk c = it*4 + w. 2-chain MFMA for ILP.
__global__ __launch_bounds__(256) void logits5_k(
    const ushort* __restrict__ glimpse, const ushort* __restrict__ lk,
    const uint* __restrict__ mbt, float* __restrict__ out) {
    int j = blockIdx.x;  // B * T/16
    int b = j & 31;
    int t0 = (j >> 5) * 16;
    int tid = threadIdx.x;
    int w = tid >> 6, l = tid & 63;
    int lo = l & 15, hi = l >> 4;

    __shared__ ushort Ls[16384];  // 64 rows x 512B, byte ^= ((row&7)<<4)
    __shared__ float reds[4][16];

    bf16x8 af[8];
    const ushort* gb = glimpse + ((size_t)(b * TT + t0 + lo)) * DD + hi * 8;
    #pragma unroll
    for (int ks = 0; ks < 8; ks++) af[ks] = *(const bf16x8*)(gb + ks * 32);
    uint mw[4];
    #pragma unroll
    for (int r = 0; r < 4; r++)
        mw[r] = mbt[((size_t)(b * TT + t0 + 4 * hi + r)) * 16 + lo];

    const f32x4 zero = {0.f, 0.f, 0.f, 0.f};
    const ushort* lkb = lk + (size_t)b * NN * DD;
    int swz = (lo & 7) << 4;
    float sum[4] = {0.f, 0.f, 0.f, 0.f};
    uint tu[16];

    for (int it = 0; it < 8; it++) {
        if (it) __syncthreads();  // prior compute done before overwrite
        #pragma unroll
        for (int i = 0; i < 8; i++) {
            int u = i * 256 + tid;
            int row = u >> 5, c16 = u & 31;
            uint4 v = *(const uint4*)(lkb + (size_t)(it * 64 + row) * 256 + c16 * 8);
            *(uint4*)((char*)Ls + (((row << 9) + (c16 << 4)) ^ ((row & 7) << 4))) = v;
        }
        __syncthreads();

        int c = it * 4 + w;  // this wave's global 16-key chunk
        f32x4 acca = zero, accb = zero;
        #pragma unroll
        for (int ks = 0; ks < 8; ks += 2) {
            bf16x8 b0 = *(const bf16x8*)((char*)Ls +
                ((((w * 16 + lo) << 9) + (ks << 6) + (hi << 4)) ^ swz));
            bf16x8 b1 = *(const bf16x8*)((char*)Ls +
                ((((w * 16 + lo) << 9) + ((ks + 1) << 6) + (hi << 4)) ^ swz));
            acca = __builtin_amdgcn_mfma_f32_16x16x32_bf16(af[ks], b0, acca, 0, 0, 0);
            accb = __builtin_amdgcn_mfma_f32_16x16x32_bf16(af[ks + 1], b1, accb, 0, 0, 0);
        }
        float t[4];
        #pragma unroll
        for (int r = 0; r < 4; r++) {
            t[r] = fast_tanh10((acca[r] + accb[r]) * 0.0625f);
            sum[r] += ((mw[r] >> c) & 1u) ? __expf(t[r] - 10.f) : 0.f;
        }
        tu[2 * it] = pk2(t[0], t[1]);
        tu[2 * it + 1] = pk2(t[2], t[3]);
    }

    #pragma unroll
    for (int r = 0; r < 4; r++)
        #pragma unroll
        for (int o = 1; o < 16; o <<= 1) sum[r] += __shfl_xor(sum[r], o);
    if (lo == 0) {
        #pragma unroll
        for (int r = 0; r < 4; r++) reds[w][4 * hi + r] = sum[r];
    }
    __syncthreads();
    float lse[4];
    #pragma unroll
    for (int r = 0; r < 4; r++) {
        int row = 4 * hi + r;
        float s = reds[0][row] + reds[1][row] + reds[2][row] + reds[3][row];
        lse[r] = 10.f + __logf(fmaxf(s, 1e-37f));
    }

    #pragma unroll
    for (int it = 0; it < 8; it++) {
        int c = it * 4 + w;
        float v[4] = {ulo(tu[2 * it]), uhi(tu[2 * it]),
                      ulo(tu[2 * it + 1]), uhi(tu[2 * it + 1])};
        #pragma unroll
        for (int r = 0; r < 4; r++) {
            float ov = ((mw[r] >> c) & 1u) ? v[r] - lse[r] : NEG_INF - lse[r];
            out[((size_t)(b * TT + t0 + 4 * hi + r)) * NN + c * 16 + lo] = ov;
        }
    }
}

// ---------------------------------------------------------------------------
extern "C" void kernel_launch(void* const* d_in, const int* in_sizes, int n_in,
                              void* d_out, int out_size, void* d_ws,
                              size_t ws_size, hipStream_t stream) {
    const float* emb = (const float*)d_in[0];
    const int* cur   = (const int*)d_in[1];
    const int* mask  = (const int*)d_in[2];
    const float* Wn  = (const float*)d_in[3];
    const float* Wf  = (const float*)d_in[4];
    const float* Ws  = (const float*)d_in[5];
    const float* Wo  = (const float*)d_in[6];
    float* out = (float*)d_out;

    const size_t SLABE = (size_t)BB * NN * DD;
    ushort* embB     = (ushort*)d_ws;
    ushort* gkT      = embB + SLABE;     // [bh][n][32]
    ushort* vTp      = gkT + SLABE;      // [bh][dh][n''] pre-permuted
    ushort* lkb      = vTp + SLABE;      // [b*N+n][256]
    ushort* gq       = lkb + SLABE;      // [b*T+t][256]
    ushort* headsB   = gq + SLABE;
    ushort* glimpseB = headsB + SLABE;
    ushort* WnT      = glimpseB + SLABE;
    ushort* WsT      = WnT + 768 * 256;
    ushort* WoT      = WsT + 256 * 256;
    uint*   mbt      = (uint*)(WoT + 256 * 256);
    float*  ctx      = (float*)(mbt + (size_t)BB * TT * 16);
    float*  partial  = ctx + (size_t)BB * DD;

    // P: fused prep (cvt+partial | transposes | packmask), then ctx
    prep_all_k<<<1600, 256, 0, stream>>>(emb, embB, partial, Wn, Ws, Wo,
                                         WnT, WsT, WoT, mask, mbt);
    ctx_mm_k<<<BB, 256, 0, stream>>>(partial, Wf, ctx);
    // K1+K2 in one dispatch
    gemm12_k<<<4096, 256, 0, stream>>>(embB, WnT, WsT, gkT, vTp, lkb, gq,
                                       ctx, cur);
    // K3: attention
    attn8_k<<<512, 256, 0, stream>>>(gq, gkT, vTp, mbt, headsB);
    // K4: glimpse = heads @ W_out
    gemm4_k<<<1024, 256, 0, stream>>>(headsB, WoT, glimpseB);
    // K5: pointer logits + log_softmax (LDS-staged)
    logits5_k<<<BB * TT / 16, 256, 0, stream>>>(glimpseB, lkb, mbt, out);
}